// Round 3
// baseline (143.323 us; speedup 1.0000x reference)
//
#include <hip/hip_runtime.h>
#include <hip/hip_bf16.h>
#include <math.h>

// ---------------------------------------------------------------------------
// HierarchicalCubeMap, round 3: LDS-cached pyramid tails.
//   launch 1: pyr_kernel builds pyr1 L1..5 and pyr0 L1..5 (RGBA float4, ws)
//   launch 2: sample_kernel caches pyr1 L5..9 + pyr0 L3..7 in LDS (65472 B,
//             tails rebuilt in-LDS from L5), samples 1M rays.
// Global fallback only for pyr1 L<=4 (~34% of rays, L2-resident) and
// pyr0 L<=2 (probability ~0).
// ---------------------------------------------------------------------------

#define NPYR1_4 524286

// level offsets in float4 units, index = level-1
__device__ __constant__ int OFFS0[7] = {0, 24576, 30720, 32256, 32640, 32736, 32760};
__device__ __constant__ int OFFS1[9] = {0, 393216, 491520, 516096, 522240,
                                        523776, 524160, 524256, 524280};
static const int H_OFFS0[7] = {0, 24576, 30720, 32256, 32640, 32736, 32760};
static const int H_OFFS1[9] = {0, 393216, 491520, 516096, 522240,
                               523776, 524160, 524256, 524280};

// LDS float4 layout (total 4092 float4 = 65472 B):
//   pyr1: L5 @0(1536) L6 @1536(384) L7 @1920(96) L8 @2016(24) L9 @2040(6)
//   pyr0: L3 @2046(1536) L4 @3582(384) L5 @3966(96) L6 @4062(24) L7 @4086(6)
__device__ __constant__ int LOFF[5] = {0, 1536, 1920, 2016, 2040};

struct PyrArgs {
    const void* src;    // source level: RGB float3
    float4* dst[5];     // 5 successive output levels (RGBA)
    int R;              // source resolution
    int tpf;            // tiles per face edge
    int T;              // tile size
    int nlev;           // levels to produce
};

// Each workgroup: load one TxT source tile to LDS (as float4), emit nlev
// successive 2x2-mean levels (matches reference's recursive pairwise mean).
__global__ __launch_bounds__(256) void pyr_kernel(PyrArgs a0, PyrArgs a1, int split) {
    __shared__ float4 A[32 * 32];
    __shared__ float4 Bb[16 * 16];

    PyrArgs a = (blockIdx.x < (unsigned)split) ? a0 : a1;
    int bid = (blockIdx.x < (unsigned)split) ? blockIdx.x : blockIdx.x - split;

    const int tpf = a.tpf;
    const int face = bid / (tpf * tpf);
    const int tif = bid - face * tpf * tpf;
    const int ty = tif / tpf, tx = tif - (tif / tpf) * tpf;
    const int T = a.T, R = a.R;
    const int tid = threadIdx.x;
    const int baseY = ty * T, baseX = tx * T;

    const int total = T * T;
    const float* src = (const float*)a.src;
    for (int idx = tid; idx < total; idx += 256) {
        int r = idx / T, c = idx - (idx / T) * T;
        const float* p = src + ((size_t)(face * R + baseY + r) * R + baseX + c) * 3;
        A[r * T + c] = make_float4(p[0], p[1], p[2], 0.f);
    }
    __syncthreads();

    float4* cur = A;
    float4* nxt = Bb;
    int curT = T;
    for (int l = 0; l < a.nlev; ++l) {
        const int nT = curT >> 1;
        const int Rg = R >> (l + 1);
        const int tb = T >> (l + 1);
        float4* dst = a.dst[l];
        const int n = nT * nT;
        for (int idx = tid; idx < n; idx += 256) {
            int ly = idx / nT, lx = idx - (idx / nT) * nT;
            float4 q00 = cur[(2 * ly) * curT + 2 * lx];
            float4 q01 = cur[(2 * ly) * curT + 2 * lx + 1];
            float4 q10 = cur[(2 * ly + 1) * curT + 2 * lx];
            float4 q11 = cur[(2 * ly + 1) * curT + 2 * lx + 1];
            float4 s = make_float4(0.25f * (q00.x + q01.x + q10.x + q11.x),
                                   0.25f * (q00.y + q01.y + q10.y + q11.y),
                                   0.25f * (q00.z + q01.z + q10.z + q11.z), 0.f);
            nxt[ly * nT + lx] = s;
            dst[(size_t)(face * Rg + ty * tb + ly) * Rg + tx * tb + lx] = s;
        }
        __syncthreads();
        float4* tmp = cur; cur = nxt; nxt = tmp;
        curT = nT;
    }
}

// ---------------- sampling helpers ----------------

__device__ __forceinline__ void wuv(int R, float u, float v, int& x0, int& x1,
                                    int& y0, int& y1, float& fx, float& fy) {
    float xf = u * (float)R - 0.5f;
    float yf = v * (float)R - 0.5f;
    float x0f = floorf(xf), y0f = floorf(yf);
    fx = xf - x0f;
    fy = yf - y0f;
    int xi = (int)x0f, yi = (int)y0f;
    x0 = min(max(xi, 0), R - 1);
    x1 = min(max(xi + 1, 0), R - 1);
    y0 = min(max(yi, 0), R - 1);
    y1 = min(max(yi + 1, 0), R - 1);
}

__device__ __forceinline__ void bilin4(const float4* __restrict__ tex, int R,
                                       int face, float u, float v, float o[3]) {
    int x0, x1, y0, y1; float fx, fy;
    wuv(R, u, v, x0, x1, y0, y1, fx, fy);
    const float4* base = tex + (size_t)face * R * R;
    float4 p00 = base[y0 * R + x0];
    float4 p01 = base[y0 * R + x1];
    float4 p10 = base[y1 * R + x0];
    float4 p11 = base[y1 * R + x1];
    float w00 = (1.f - fx) * (1.f - fy), w01 = fx * (1.f - fy);
    float w10 = (1.f - fx) * fy, w11 = fx * fy;
    o[0] = w00 * p00.x + w01 * p01.x + w10 * p10.x + w11 * p11.x;
    o[1] = w00 * p00.y + w01 * p01.y + w10 * p10.y + w11 * p11.y;
    o[2] = w00 * p00.z + w01 * p01.z + w10 * p10.z + w11 * p11.z;
}

__device__ __forceinline__ void bilin3(const float* __restrict__ tex, int R,
                                       int face, float u, float v, float o[3]) {
    int x0, x1, y0, y1; float fx, fy;
    wuv(R, u, v, x0, x1, y0, y1, fx, fy);
    const float* base = tex + (size_t)face * R * R * 3;
    const float* p00 = base + (y0 * R + x0) * 3;
    const float* p01 = base + (y0 * R + x1) * 3;
    const float* p10 = base + (y1 * R + x0) * 3;
    const float* p11 = base + (y1 * R + x1) * 3;
    float w00 = (1.f - fx) * (1.f - fy), w01 = fx * (1.f - fy);
    float w10 = (1.f - fx) * fy, w11 = fx * fy;
#pragma unroll
    for (int c = 0; c < 3; ++c)
        o[c] = w00 * p00[c] + w01 * p01[c] + w10 * p10[c] + w11 * p11[c];
}

__device__ __forceinline__ void bilinL(const float4* __restrict__ L, int lb, int R,
                                       int face, float u, float v, float o[3]) {
    int x0, x1, y0, y1; float fx, fy;
    wuv(R, u, v, x0, x1, y0, y1, fx, fy);
    const float4* base = L + lb + face * R * R;
    float4 p00 = base[y0 * R + x0];
    float4 p01 = base[y0 * R + x1];
    float4 p10 = base[y1 * R + x0];
    float4 p11 = base[y1 * R + x1];
    float w00 = (1.f - fx) * (1.f - fy), w01 = fx * (1.f - fy);
    float w10 = (1.f - fx) * fy, w11 = fx * fy;
    o[0] = w00 * p00.x + w01 * p01.x + w10 * p10.x + w11 * p11.x;
    o[1] = w00 * p00.y + w01 * p01.y + w10 * p10.y + w11 * p11.y;
    o[2] = w00 * p00.z + w01 * p01.z + w10 * p10.z + w11 * p11.z;
}

// tap pyramid 1 (512 base, lmax 9): LDS for level>=5
__device__ __forceinline__ void tap1(const float4* __restrict__ L,
                                     const float* __restrict__ tex1,
                                     const float4* __restrict__ pyr1, int l,
                                     int face, float u, float v, float o[3]) {
    if (l >= 5)      bilinL(L, LOFF[l - 5], 16 >> (l - 5), face, u, v, o);
    else if (l >= 1) bilin4(pyr1 + OFFS1[l - 1], 512 >> l, face, u, v, o);
    else             bilin3(tex1, 512, face, u, v, o);
}

// tap pyramid 0 (128 base, lmax 7): LDS for level>=3
__device__ __forceinline__ void tap0(const float4* __restrict__ L,
                                     const float* __restrict__ tex0,
                                     const float4* __restrict__ pyr0, int l,
                                     int face, float u, float v, float o[3]) {
    if (l >= 3)      bilinL(L, 2046 + LOFF[l - 3], 16 >> (l - 3), face, u, v, o);
    else if (l >= 1) bilin4(pyr0 + OFFS0[l - 1], 128 >> l, face, u, v, o);
    else             bilin3(tex0, 128, face, u, v, o);
}

// in-LDS 2x2 mean reduction: src base sb (res sr/face), dst base db
__device__ __forceinline__ void lds_reduce(float4* L, int sb, int sr, int db,
                                           int tid) {
    int dr = sr >> 1;
    int n = 6 * dr * dr;
    for (int idx = tid; idx < n; idx += 256) {
        int f = idx / (dr * dr);
        int rem = idx - f * dr * dr;
        int y = rem / dr, x = rem - y * dr;
        const float4* s = L + sb + f * sr * sr;
        float4 q00 = s[(2 * y) * sr + 2 * x];
        float4 q01 = s[(2 * y) * sr + 2 * x + 1];
        float4 q10 = s[(2 * y + 1) * sr + 2 * x];
        float4 q11 = s[(2 * y + 1) * sr + 2 * x + 1];
        L[db + f * dr * dr + y * dr + x] =
            make_float4(0.25f * (q00.x + q01.x + q10.x + q11.x),
                        0.25f * (q00.y + q01.y + q10.y + q11.y),
                        0.25f * (q00.z + q01.z + q10.z + q11.z), 0.f);
    }
}

__global__ __launch_bounds__(256) void sample_kernel(
    const float* __restrict__ vd, const float* __restrict__ sa,
    const float* __restrict__ nu, const float* __restrict__ tex0,
    const float* __restrict__ tex1, const float* __restrict__ sb,
    const float* __restrict__ sm, const float* __restrict__ smb,
    const float4* __restrict__ pyr0, const float4* __restrict__ pyr1,
    float* __restrict__ out, int n) {
    __shared__ float4 L[4092];
    const int tid = threadIdx.x;

    // --- fill LDS cache: pyr1 L5, pyr0 L3..5 from ws ---
    for (int i = tid; i < 1536; i += 256) L[i] = pyr1[OFFS1[4] + i];
    for (int i = tid; i < 1536; i += 256) L[2046 + i] = pyr0[OFFS0[2] + i];
    for (int i = tid; i < 384; i += 256)  L[3582 + i] = pyr0[OFFS0[3] + i];
    for (int i = tid; i < 96; i += 256)   L[3966 + i] = pyr0[OFFS0[4] + i];
    __syncthreads();
    // --- rebuild tails in LDS ---
    lds_reduce(L, 0, 16, 1536, tid);        // pyr1 L6
    lds_reduce(L, 3966, 4, 4062, tid);      // pyr0 L6
    __syncthreads();
    lds_reduce(L, 1536, 8, 1920, tid);      // pyr1 L7
    lds_reduce(L, 4062, 2, 4086, tid);      // pyr0 L7
    __syncthreads();
    lds_reduce(L, 1920, 4, 2016, tid);      // pyr1 L8
    __syncthreads();
    lds_reduce(L, 2016, 2, 2040, tid);      // pyr1 L9
    __syncthreads();

    const float brightness = fminf(fmaxf(sb[0], -1.f), 2.f);
    const float mul = sm[0];
    const float mipbias = smb[0];

    const int stride = gridDim.x * 256;
    for (int i = blockIdx.x * 256 + tid; i < n; i += stride) {
        float x = vd[3 * i + 0];
        float y = vd[3 * i + 1];
        float z = vd[3 * i + 2];
        float ax = fabsf(x), ay = fabsf(y), az = fabsf(z);

        bool is_x = (ax >= ay) && (ax >= az);
        bool is_y = (!is_x) && (ay >= az);

        int face;
        float ma, sc, tc;
        if (is_x) {
            face = (x >= 0.f) ? 0 : 1;
            ma = ax; sc = (x >= 0.f) ? -z : z; tc = -y;
        } else if (is_y) {
            face = (y >= 0.f) ? 2 : 3;
            ma = ay; sc = x; tc = (y >= 0.f) ? z : -z;
        } else {
            face = (z >= 0.f) ? 4 : 5;
            ma = az; sc = (z >= 0.f) ? x : -x; tc = -y;
        }
        float u = 0.5f * (sc / ma + 1.f);
        float t = 0.5f * (tc / ma + 1.f);

        float saTexel = (1.f / ma) / 512.f / 512.f;
        float mip = (sa[i] - logf(saTexel)) / 1.3862943611198906f / 2.0f +
                    mipbias + 0.5f * nu[i];
        mip = fmaxf(mip, 0.f);

        // pyramid 0 (lmax 7)
        float s0[3];
        {
            float m = fminf(mip, 7.f);
            float l0f = floorf(m);
            int l0 = (int)l0f;
            float f = m - l0f;
            tap0(L, tex0, pyr0, l0, face, u, t, s0);
            if (f > 0.f && l0 < 7) {
                float c1[3];
                tap0(L, tex0, pyr0, l0 + 1, face, u, t, c1);
                float w0 = 1.f - f;
#pragma unroll
                for (int c = 0; c < 3; ++c) s0[c] = w0 * s0[c] + f * c1[c];
            }
        }
        // pyramid 1 (lmax 9)
        float s1[3];
        {
            float m = fminf(mip, 9.f);
            float l0f = floorf(m);
            int l0 = (int)l0f;
            float f = m - l0f;
            tap1(L, tex1, pyr1, l0, face, u, t, s1);
            if (f > 0.f && l0 < 9) {
                float c1[3];
                tap1(L, tex1, pyr1, l0 + 1, face, u, t, c1);
                float w0 = 1.f - f;
#pragma unroll
                for (int c = 0; c < 3; ++c) s1[c] = w0 * s1[c] + f * c1[c];
            }
        }

#pragma unroll
        for (int c = 0; c < 3; ++c) {
            float e = expf(brightness + mul * (s0[c] + s1[c]));
            out[3 * i + c] = fminf(fmaxf(e, 0.01f), 1000.f);
        }
    }
}

extern "C" void kernel_launch(void* const* d_in, const int* in_sizes, int n_in,
                              void* d_out, int out_size, void* d_ws, size_t ws_size,
                              hipStream_t stream) {
    const float* vd = (const float*)d_in[0];
    const float* sa = (const float*)d_in[1];
    const float* nu = (const float*)d_in[2];
    const float* tex0 = (const float*)d_in[3];  // (6,128,128,3)
    const float* tex1 = (const float*)d_in[4];  // (6,512,512,3)
    const float* br = (const float*)d_in[5];
    const float* mu = (const float*)d_in[6];
    const float* mb = (const float*)d_in[7];
    float* out = (float*)d_out;

    float4* pyr1 = (float4*)d_ws;
    float4* pyr0 = pyr1 + NPYR1_4;

    const int B = in_sizes[1];

    // --- pyramid build: levels 1..5 of each (tails rebuilt in sample_kernel) ---
    PyrArgs a0{}, a1{};
    a0.src = tex1; a0.R = 512; a0.tpf = 16; a0.T = 32; a0.nlev = 5;
    for (int l = 0; l < 5; ++l) a0.dst[l] = pyr1 + H_OFFS1[l];
    a1.src = tex0; a1.R = 128; a1.tpf = 4; a1.T = 32; a1.nlev = 5;
    for (int l = 0; l < 5; ++l) a1.dst[l] = pyr0 + H_OFFS0[l];
    int split1 = 6 * 16 * 16;
    int grid1 = split1 + 6 * 4 * 4;
    hipLaunchKernelGGL(pyr_kernel, dim3(grid1), dim3(256), 0, stream, a0, a1, split1);

    // --- sampling: 512 blocks (2/CU, LDS-limited), grid-stride ---
    hipLaunchKernelGGL(sample_kernel, dim3(512), dim3(256), 0, stream,
                       vd, sa, nu, tex0, tex1, br, mu, mb, pyr0, pyr1, out, B);
}

// Round 4
// 138.642 us; speedup vs baseline: 1.0338x; 1.0338x over previous
//
#include <hip/hip_runtime.h>
#include <hip/hip_bf16.h>
#include <hip/hip_fp16.h>
#include <math.h>

// ---------------------------------------------------------------------------
// HierarchicalCubeMap, round 4: fp16 (half4, 8 B) pyramid texels.
//   launch 1: pyr_kernel builds pyr1 L1..5 + pyr0 L1..5 into ws as half4
//             (fp32 averaging chain, fp16 storage only).
//   launch 2: sample_kernel caches pyr1 L5..9 + pyr0 L3..7 in LDS
//             (32736 B -> 5 blocks/CU), tails rebuilt in-LDS; global fp16
//             taps only for pyr1 L1..4 / pyr0 L1..2; fp32 base for L0.
// Global level offsets (half4 units):
//   pyr1 l=1..5: 524288 - (524288 >> 2(l-1))  -> 0,393216,491520,516096,522240
//   pyr0 l=1..5: 32768  - (32768  >> 2(l-1))  -> 0,24576,30720,32256,32640
//   pyr0 base at 524288 half4 from ws start.
// LDS layout (half4 units): pyr1 j=l-5 @ 2048-(2048>>2j); pyr0 j=l-3 @ 2046+same.
// ---------------------------------------------------------------------------

struct __align__(8) H4 { __half x, y, z, w; };

#define PYR0_WS_BASE 524288

__device__ __forceinline__ H4 f2h4(float a, float b, float c) {
    H4 h;
    h.x = __float2half(a); h.y = __float2half(b); h.z = __float2half(c);
    h.w = __float2half(0.f);
    return h;
}

struct PyrArgs {
    const float* src;   // source level, RGB fp32 (6,R,R,3)
    H4* dst[5];         // 5 successive output levels (half4)
    int R;
    int tpf;
    int T;
    int nlev;
};

// Workgroup: load one TxT RGB tile to LDS (fp32, vectorized float4 reads),
// emit nlev successive 2x2-mean levels (fp32 chain, fp16 global stores).
__global__ __launch_bounds__(256) void pyr_kernel(PyrArgs a0, PyrArgs a1, int split) {
    __shared__ float4 A[32 * 32];
    __shared__ float4 Bb[16 * 16];

    PyrArgs a = (blockIdx.x < (unsigned)split) ? a0 : a1;
    int bid = (blockIdx.x < (unsigned)split) ? blockIdx.x : blockIdx.x - split;

    const int tpf = a.tpf;
    const int face = bid / (tpf * tpf);
    const int tif = bid - face * tpf * tpf;
    const int ty = tif / tpf, tx = tif - (tif / tpf) * tpf;
    const int T = a.T, R = a.R;
    const int tid = threadIdx.x;
    const int baseY = ty * T, baseX = tx * T;

    // vectorized tile load: 4 texels (48 B = 3 float4) per group
    const int ngroups = (T * T) >> 2;
    for (int g = tid; g < ngroups; g += 256) {
        int r = (g * 4) / T, c = (g * 4) - ((g * 4) / T) * T;
        const float4* p = (const float4*)(a.src +
            ((size_t)(face * R + baseY + r) * R + baseX + c) * 3);
        float4 q0 = p[0], q1 = p[1], q2 = p[2];
        float4* dst = &A[r * T + c];
        dst[0] = make_float4(q0.x, q0.y, q0.z, 0.f);
        dst[1] = make_float4(q0.w, q1.x, q1.y, 0.f);
        dst[2] = make_float4(q1.z, q1.w, q2.x, 0.f);
        dst[3] = make_float4(q2.y, q2.z, q2.w, 0.f);
    }
    __syncthreads();

    float4* cur = A;
    float4* nxt = Bb;
    int curT = T;
    for (int l = 0; l < a.nlev; ++l) {
        const int nT = curT >> 1;
        const int Rg = R >> (l + 1);
        const int tb = T >> (l + 1);
        H4* dst = a.dst[l];
        const int n = nT * nT;
        for (int idx = tid; idx < n; idx += 256) {
            int ly = idx / nT, lx = idx - (idx / nT) * nT;
            float4 q00 = cur[(2 * ly) * curT + 2 * lx];
            float4 q01 = cur[(2 * ly) * curT + 2 * lx + 1];
            float4 q10 = cur[(2 * ly + 1) * curT + 2 * lx];
            float4 q11 = cur[(2 * ly + 1) * curT + 2 * lx + 1];
            float sx = 0.25f * (q00.x + q01.x + q10.x + q11.x);
            float sy = 0.25f * (q00.y + q01.y + q10.y + q11.y);
            float sz = 0.25f * (q00.z + q01.z + q10.z + q11.z);
            nxt[ly * nT + lx] = make_float4(sx, sy, sz, 0.f);
            dst[(size_t)(face * Rg + ty * tb + ly) * Rg + tx * tb + lx] =
                f2h4(sx, sy, sz);
        }
        __syncthreads();
        float4* tmp = cur; cur = nxt; nxt = tmp;
        curT = nT;
    }
}

// ---------------- sampling helpers ----------------

__device__ __forceinline__ void wuv(int R, float u, float v, int& x0, int& x1,
                                    int& y0, int& y1, float& fx, float& fy) {
    float xf = u * (float)R - 0.5f;
    float yf = v * (float)R - 0.5f;
    float x0f = floorf(xf), y0f = floorf(yf);
    fx = xf - x0f;
    fy = yf - y0f;
    int xi = (int)x0f, yi = (int)y0f;
    x0 = min(max(xi, 0), R - 1);
    x1 = min(max(xi + 1, 0), R - 1);
    y0 = min(max(yi, 0), R - 1);
    y1 = min(max(yi + 1, 0), R - 1);
}

__device__ __forceinline__ void mix4(H4 p00, H4 p01, H4 p10, H4 p11,
                                     float fx, float fy, float o[3]) {
    float w00 = (1.f - fx) * (1.f - fy), w01 = fx * (1.f - fy);
    float w10 = (1.f - fx) * fy, w11 = fx * fy;
    o[0] = w00 * __half2float(p00.x) + w01 * __half2float(p01.x) +
           w10 * __half2float(p10.x) + w11 * __half2float(p11.x);
    o[1] = w00 * __half2float(p00.y) + w01 * __half2float(p01.y) +
           w10 * __half2float(p10.y) + w11 * __half2float(p11.y);
    o[2] = w00 * __half2float(p00.z) + w01 * __half2float(p01.z) +
           w10 * __half2float(p10.z) + w11 * __half2float(p11.z);
}

__device__ __forceinline__ void bilinG(const H4* __restrict__ t, int R,
                                       int face, float u, float v, float o[3]) {
    int x0, x1, y0, y1; float fx, fy;
    wuv(R, u, v, x0, x1, y0, y1, fx, fy);
    const H4* b = t + face * R * R;
    mix4(b[y0 * R + x0], b[y0 * R + x1], b[y1 * R + x0], b[y1 * R + x1],
         fx, fy, o);
}

// LDS bilinear (separate function so loads stay ds_read, not flat)
__device__ __forceinline__ void bilinL(const H4* L, int lb, int R,
                                       int face, float u, float v, float o[3]) {
    int x0, x1, y0, y1; float fx, fy;
    wuv(R, u, v, x0, x1, y0, y1, fx, fy);
    int b = lb + face * R * R;
    mix4(L[b + y0 * R + x0], L[b + y0 * R + x1],
         L[b + y1 * R + x0], L[b + y1 * R + x1], fx, fy, o);
}

__device__ __forceinline__ void bilin3(const float* __restrict__ tex, int R,
                                       int face, float u, float v, float o[3]) {
    int x0, x1, y0, y1; float fx, fy;
    wuv(R, u, v, x0, x1, y0, y1, fx, fy);
    const float* base = tex + (size_t)face * R * R * 3;
    const float* p00 = base + (y0 * R + x0) * 3;
    const float* p01 = base + (y0 * R + x1) * 3;
    const float* p10 = base + (y1 * R + x0) * 3;
    const float* p11 = base + (y1 * R + x1) * 3;
    float w00 = (1.f - fx) * (1.f - fy), w01 = fx * (1.f - fy);
    float w10 = (1.f - fx) * fy, w11 = fx * fy;
#pragma unroll
    for (int c = 0; c < 3; ++c)
        o[c] = w00 * p00[c] + w01 * p01[c] + w10 * p10[c] + w11 * p11[c];
}

// in-LDS 2x2 mean reduction on half4 levels (fp32 math)
__device__ __forceinline__ void lds_reduce(H4* L, int sb, int sr, int db, int tid) {
    int dr = sr >> 1;
    int n = 6 * dr * dr;
    for (int idx = tid; idx < n; idx += 256) {
        int f = idx / (dr * dr);
        int rem = idx - f * dr * dr;
        int y = rem / dr, x = rem - y * dr;
        const H4* s = L + sb + f * sr * sr;
        H4 q00 = s[(2 * y) * sr + 2 * x];
        H4 q01 = s[(2 * y) * sr + 2 * x + 1];
        H4 q10 = s[(2 * y + 1) * sr + 2 * x];
        H4 q11 = s[(2 * y + 1) * sr + 2 * x + 1];
        L[db + f * dr * dr + y * dr + x] = f2h4(
            0.25f * (__half2float(q00.x) + __half2float(q01.x) +
                     __half2float(q10.x) + __half2float(q11.x)),
            0.25f * (__half2float(q00.y) + __half2float(q01.y) +
                     __half2float(q10.y) + __half2float(q11.y)),
            0.25f * (__half2float(q00.z) + __half2float(q01.z) +
                     __half2float(q10.z) + __half2float(q11.z)));
    }
}

// pyr1 tap: LDS for l>=5, global half4 for 1..4, fp32 base for 0
__device__ __forceinline__ void tap1(const H4* L, const float* __restrict__ tex1,
                                     const H4* __restrict__ g1, int l,
                                     int face, float u, float v, float o[3]) {
    if (l >= 5) {
        int j = l - 5;
        bilinL(L, 2048 - (2048 >> (2 * j)), 16 >> j, face, u, v, o);
    } else if (l >= 1) {
        bilinG(g1 + (524288 - (524288 >> (2 * (l - 1)))), 512 >> l, face, u, v, o);
    } else {
        bilin3(tex1, 512, face, u, v, o);
    }
}

// pyr0 tap: LDS for l>=3, global half4 for 1..2, fp32 base for 0
__device__ __forceinline__ void tap0(const H4* L, const float* __restrict__ tex0,
                                     const H4* __restrict__ g0, int l,
                                     int face, float u, float v, float o[3]) {
    if (l >= 3) {
        int j = l - 3;
        bilinL(L, 2046 + 2048 - (2048 >> (2 * j)), 16 >> j, face, u, v, o);
    } else if (l >= 1) {
        bilinG(g0 + (32768 - (32768 >> (2 * (l - 1)))), 128 >> l, face, u, v, o);
    } else {
        bilin3(tex0, 128, face, u, v, o);
    }
}

__global__ __launch_bounds__(256) void sample_kernel(
    const float* __restrict__ vd, const float* __restrict__ sa,
    const float* __restrict__ nu, const float* __restrict__ tex0,
    const float* __restrict__ tex1, const float* __restrict__ sb,
    const float* __restrict__ sm, const float* __restrict__ smb,
    const H4* __restrict__ g1, const H4* __restrict__ g0,
    float* __restrict__ out, int n) {
    __shared__ H4 L[4092];   // 32736 B -> 5 blocks/CU
    const int tid = threadIdx.x;

    // fill LDS: pyr1 L5 (@0,1536), pyr0 L3 (@2046,1536) L4 (@3582,384) L5 (@3966,96)
    for (int i = tid; i < 1536; i += 256) L[i] = g1[522240 + i];
    for (int i = tid; i < 1536; i += 256) L[2046 + i] = g0[30720 + i];
    for (int i = tid; i < 384; i += 256)  L[3582 + i] = g0[32256 + i];
    for (int i = tid; i < 96; i += 256)   L[3966 + i] = g0[32640 + i];
    __syncthreads();
    lds_reduce(L, 0, 16, 1536, tid);      // pyr1 L6
    lds_reduce(L, 3966, 4, 4062, tid);    // pyr0 L6
    __syncthreads();
    lds_reduce(L, 1536, 8, 1920, tid);    // pyr1 L7
    lds_reduce(L, 4062, 2, 4086, tid);    // pyr0 L7
    __syncthreads();
    lds_reduce(L, 1920, 4, 2016, tid);    // pyr1 L8
    __syncthreads();
    lds_reduce(L, 2016, 2, 2040, tid);    // pyr1 L9
    __syncthreads();

    const float brightness = fminf(fmaxf(sb[0], -1.f), 2.f);
    const float mul = sm[0];
    const float mipbias = smb[0];

    const int stride = gridDim.x * 256;
    for (int i = blockIdx.x * 256 + tid; i < n; i += stride) {
        float x = vd[3 * i + 0];
        float y = vd[3 * i + 1];
        float z = vd[3 * i + 2];
        float ax = fabsf(x), ay = fabsf(y), az = fabsf(z);

        bool is_x = (ax >= ay) && (ax >= az);
        bool is_y = (!is_x) && (ay >= az);

        int face;
        float ma, sc, tc;
        if (is_x) {
            face = (x >= 0.f) ? 0 : 1;
            ma = ax; sc = (x >= 0.f) ? -z : z; tc = -y;
        } else if (is_y) {
            face = (y >= 0.f) ? 2 : 3;
            ma = ay; sc = x; tc = (y >= 0.f) ? z : -z;
        } else {
            face = (z >= 0.f) ? 4 : 5;
            ma = az; sc = (z >= 0.f) ? x : -x; tc = -y;
        }
        float u = 0.5f * (sc / ma + 1.f);
        float t = 0.5f * (tc / ma + 1.f);

        float saTexel = (1.f / ma) / 512.f / 512.f;
        float mip = (sa[i] - logf(saTexel)) / 1.3862943611198906f / 2.0f +
                    mipbias + 0.5f * nu[i];
        mip = fmaxf(mip, 0.f);

        // pyramid 0 (lmax 7)
        float s0[3];
        {
            float m = fminf(mip, 7.f);
            float l0f = floorf(m);
            int l0 = (int)l0f;
            float f = m - l0f;
            tap0(L, tex0, g0, l0, face, u, t, s0);
            if (f > 0.f && l0 < 7) {
                float c1[3];
                tap0(L, tex0, g0, l0 + 1, face, u, t, c1);
                float w0 = 1.f - f;
#pragma unroll
                for (int c = 0; c < 3; ++c) s0[c] = w0 * s0[c] + f * c1[c];
            }
        }
        // pyramid 1 (lmax 9)
        float s1[3];
        {
            float m = fminf(mip, 9.f);
            float l0f = floorf(m);
            int l0 = (int)l0f;
            float f = m - l0f;
            tap1(L, tex1, g1, l0, face, u, t, s1);
            if (f > 0.f && l0 < 9) {
                float c1[3];
                tap1(L, tex1, g1, l0 + 1, face, u, t, c1);
                float w0 = 1.f - f;
#pragma unroll
                for (int c = 0; c < 3; ++c) s1[c] = w0 * s1[c] + f * c1[c];
            }
        }

#pragma unroll
        for (int c = 0; c < 3; ++c) {
            float e = expf(brightness + mul * (s0[c] + s1[c]));
            out[3 * i + c] = fminf(fmaxf(e, 0.01f), 1000.f);
        }
    }
}

extern "C" void kernel_launch(void* const* d_in, const int* in_sizes, int n_in,
                              void* d_out, int out_size, void* d_ws, size_t ws_size,
                              hipStream_t stream) {
    const float* vd = (const float*)d_in[0];
    const float* sa = (const float*)d_in[1];
    const float* nu = (const float*)d_in[2];
    const float* tex0 = (const float*)d_in[3];  // (6,128,128,3)
    const float* tex1 = (const float*)d_in[4];  // (6,512,512,3)
    const float* br = (const float*)d_in[5];
    const float* mu = (const float*)d_in[6];
    const float* mb = (const float*)d_in[7];
    float* out = (float*)d_out;

    H4* g1 = (H4*)d_ws;                 // pyr1 levels 1..5
    H4* g0 = g1 + PYR0_WS_BASE;         // pyr0 levels 1..5

    const int B = in_sizes[1];

    static const int O1[5] = {0, 393216, 491520, 516096, 522240};
    static const int O0[5] = {0, 24576, 30720, 32256, 32640};

    PyrArgs a0{}, a1{};
    a0.src = tex1; a0.R = 512; a0.tpf = 16; a0.T = 32; a0.nlev = 5;
    for (int l = 0; l < 5; ++l) a0.dst[l] = g1 + O1[l];
    a1.src = tex0; a1.R = 128; a1.tpf = 4; a1.T = 32; a1.nlev = 5;
    for (int l = 0; l < 5; ++l) a1.dst[l] = g0 + O0[l];
    int split1 = 6 * 16 * 16;
    int grid1 = split1 + 6 * 4 * 4;
    hipLaunchKernelGGL(pyr_kernel, dim3(grid1), dim3(256), 0, stream, a0, a1, split1);

    // 1280 blocks = 5 resident blocks/CU * 256 CUs, grid-stride
    hipLaunchKernelGGL(sample_kernel, dim3(1280), dim3(256), 0, stream,
                       vd, sa, nu, tex0, tex1, br, mu, mb, g1, g0, out, B);
}